// Round 13
// baseline (147.272 us; speedup 1.0000x reference)
//
#include <hip/hip_runtime.h>
#include <cmath>

#define CTXL 50
#define NC 300    // NCOND
#define NH 256    // NHID
#define NT 256    // threads per block
#define KPAD 320  // K padded to 10 k-steps of 32
#define ASTR 328  // LDS A row stride in shorts (656 B)
#define MR 32     // K1 rows per tile
#define NKS 10    // k-steps

typedef float  f32x4 __attribute__((ext_vector_type(4)));
typedef short  s16x8 __attribute__((ext_vector_type(8)));
typedef short  s16x4 __attribute__((ext_vector_type(4)));

__device__ __forceinline__ ushort f2bf(float f) {
    unsigned u = __float_as_uint(f);
    unsigned r = (u + 0x7FFFu + ((u >> 16) & 1u)) >> 16;   // RNE
    return (ushort)r;
}
__device__ __forceinline__ float bf2f(ushort u) {
    return __uint_as_float(((unsigned)u) << 16);
}

// ---------------------------------------------------------------------------
// prepass: W1 [300][256] -> W1T bf16 [256][320]; W2 [256][300] -> W2T bf16 [300][256]
__global__ void convert_w(const float* __restrict__ W1, const float* __restrict__ W2,
                          ushort* __restrict__ W1T, ushort* __restrict__ W2T) {
    const int t  = threadIdx.x;
    const int bi = blockIdx.x;
    if (bi < KPAD) {
        W1T[(size_t)t * KPAD + bi] = (bi < NC) ? f2bf(W1[(size_t)bi * NH + t]) : (ushort)0;
    } else {
        const int j = bi - KPAD;           // < 300
        W2T[(size_t)j * NH + t] = f2bf(W2[(size_t)t * NC + j]);
    }
}

// ---------------------------------------------------------------------------
// K1 v6: H[ntok][256] bf16 = relu(embs @ W1 + b1).
// ROUND-12 LESSON: the W1T register preload (160 regs in the unified
// VGPR/AGPR file on top of the reported 128) capped residency at ~6 waves/CU
// AND starved the staging loop of registers (loads serialized). DROPPED.
// W1T fragments now come from L2 per k-step (160KB table, L2/L3-resident);
// with ~4 blocks/CU x 4 waves the ~200cyc L2 latency hides under MFMA.
// One tile per block (grid = ntiles), stage->barrier->MFMA->store.
// LESSON (r3/r4/r5/r11): never hold staged regs live across the MFMA region.
__global__ __launch_bounds__(NT, 4)
void k1_hidden(const float* __restrict__ embs,
               const float* __restrict__ b1,
               const ushort* __restrict__ W1T,
               ushort* __restrict__ H, int ntok) {
    __shared__ short A[MR * ASTR];        // 20992 B
    const int tid  = threadIdx.x;
    const int wave = tid >> 6;
    const int lane = tid & 63;
    const int l15  = lane & 15;
    const int lhi  = lane >> 4;
    const int m0   = blockIdx.x * MR;

    // ---- stage MR rows fp32 -> bf16 LDS (coalesced, 5 chunks/thread) ------
    #pragma unroll
    for (int i = 0; i < MR * 40 / NT; ++i) {
        const int g = tid + NT * i;
        const int r = g / 40;
        const int c = g - r * 40;                // 16B chunk 0..39
        int row = m0 + r; if (row >= ntok) row = ntok - 1;
        const float* src = embs + (size_t)row * NC + c * 8;
        float v[8];
        if (c < 37) {
            const float4 a0 = *(const float4*)src;
            const float4 a1 = *(const float4*)(src + 4);
            v[0]=a0.x; v[1]=a0.y; v[2]=a0.z; v[3]=a0.w;
            v[4]=a1.x; v[5]=a1.y; v[6]=a1.z; v[7]=a1.w;
        } else if (c == 37) {
            const float4 a0 = *(const float4*)src;
            v[0]=a0.x; v[1]=a0.y; v[2]=a0.z; v[3]=a0.w;
            v[4]=v[5]=v[6]=v[7]=0.0f;
        } else {
            #pragma unroll
            for (int q = 0; q < 8; ++q) v[q] = 0.0f;
        }
        s16x8 p;
        #pragma unroll
        for (int q = 0; q < 8; ++q) p[q] = (short)f2bf(v[q]);
        *(s16x8*)((char*)A + (size_t)r * (ASTR * 2) + c * 16) = p;
    }
    __syncthreads();

    // ---- MFMA: W1T frags from L2 per k-step + A frags from LDS ------------
    const ushort* wbase = W1T + (size_t)(wave * 64 + l15) * KPAD + lhi * 8;

    f32x4 acc[4][2];
    #pragma unroll
    for (int ct = 0; ct < 4; ++ct)
        #pragma unroll
        for (int rt = 0; rt < 2; ++rt)
            acc[ct][rt] = (f32x4){0.f, 0.f, 0.f, 0.f};

    #pragma unroll
    for (int ks = 0; ks < NKS; ++ks) {
        s16x8 wf[4], ef[2];
        #pragma unroll
        for (int ct = 0; ct < 4; ++ct)
            wf[ct] = *(const s16x8*)(wbase + ct * 16 * KPAD + ks * 32);
        #pragma unroll
        for (int rt = 0; rt < 2; ++rt)
            ef[rt] = *(const s16x8*)((const char*)A +
                        (size_t)(rt * 16 + l15) * (ASTR * 2) + ks * 64 + lhi * 16);
        #pragma unroll
        for (int ct = 0; ct < 4; ++ct)
            #pragma unroll
            for (int rt = 0; rt < 2; ++rt)
                acc[ct][rt] = __builtin_amdgcn_mfma_f32_16x16x32_bf16(
                    wf[ct], ef[rt], acc[ct][rt], 0, 0, 0);
    }

    // ---- epilogue: relu(acc + b1) -> bf16, direct ushort4 stores ----------
    // swapped-MFMA layout: D-col(l15)=emb row, D-row(4*lhi+q)=W1 col
    #pragma unroll
    for (int ct = 0; ct < 4; ++ct) {
        const int col = wave * 64 + ct * 16 + 4 * lhi;
        const float4 b4 = *(const float4*)(b1 + col);
        #pragma unroll
        for (int rt = 0; rt < 2; ++rt) {
            const int row = m0 + rt * 16 + l15;
            if (row < ntok) {
                ushort4 h;
                h.x = f2bf(fmaxf(acc[ct][rt][0] + b4.x, 0.0f));
                h.y = f2bf(fmaxf(acc[ct][rt][1] + b4.y, 0.0f));
                h.z = f2bf(fmaxf(acc[ct][rt][2] + b4.z, 0.0f));
                h.w = f2bf(fmaxf(acc[ct][rt][3] + b4.w, 0.0f));
                *(ushort4*)(H + (size_t)row * NH + col) = h;
            }
        }
    }
}

// ---------------------------------------------------------------------------
// K2: out[b] = sigmoid(mean_l H[ctx[b,l]] @ W2 + b2) * embs[x[b]]
// 4 samples per block: wave w pools its sample's 50 rows; W2T row stream
// shared by 4 gates.
__global__ __launch_bounds__(NT, 4)
void k2_pool(const int* __restrict__ x,
             const int* __restrict__ ctx,
             const float* __restrict__ embs,
             const ushort* __restrict__ H,
             const ushort* __restrict__ W2T,
             const float* __restrict__ b2,
             float* __restrict__ out) {
    __shared__ int   ctxs[4 * CTXL];
    __shared__ float pooled[4][NH];
    const int b0   = blockIdx.x * 4;
    const int tid  = threadIdx.x;
    const int wave = tid >> 6;
    const int lane = tid & 63;

    if (tid < 4 * CTXL) ctxs[tid] = ctx[b0 * CTXL + tid];   // contiguous
    __syncthreads();

    {
        float4 ps = make_float4(0.f, 0.f, 0.f, 0.f);
        #pragma unroll 10
        for (int i = 0; i < CTXL; ++i) {
            const int row = ctxs[wave * CTXL + i];
            const s16x4 h4 = *(const s16x4*)(H + (size_t)row * NH + lane * 4);
            ps.x += bf2f((ushort)h4[0]);
            ps.y += bf2f((ushort)h4[1]);
            ps.z += bf2f((ushort)h4[2]);
            ps.w += bf2f((ushort)h4[3]);
        }
        ps.x *= (1.0f / CTXL); ps.y *= (1.0f / CTXL);
        ps.z *= (1.0f / CTXL); ps.w *= (1.0f / CTXL);
        *(float4*)(&pooled[wave][lane * 4]) = ps;
    }
    __syncthreads();

    const int x0 = x[b0], x1 = x[b0 + 1], x2 = x[b0 + 2], x3 = x[b0 + 3];
    for (int j = tid; j < NC; j += NT) {
        float s0 = b2[j], s1 = s0, s2 = s0, s3 = s0;
        const s16x8* wrow = (const s16x8*)(W2T + (size_t)j * NH);
        #pragma unroll 8
        for (int c = 0; c < NH / 8; ++c) {
            const s16x8 w8 = wrow[c];
            #pragma unroll
            for (int q = 0; q < 8; ++q) {
                const float wv = bf2f((ushort)w8[q]);
                s0 = fmaf(pooled[0][c * 8 + q], wv, s0);
                s1 = fmaf(pooled[1][c * 8 + q], wv, s1);
                s2 = fmaf(pooled[2][c * 8 + q], wv, s2);
                s3 = fmaf(pooled[3][c * 8 + q], wv, s3);
            }
        }
        out[(size_t)(b0 + 0) * NC + j] =
            (1.0f / (1.0f + __expf(-s0))) * embs[(size_t)x0 * NC + j];
        out[(size_t)(b0 + 1) * NC + j] =
            (1.0f / (1.0f + __expf(-s1))) * embs[(size_t)x1 * NC + j];
        out[(size_t)(b0 + 2) * NC + j] =
            (1.0f / (1.0f + __expf(-s2))) * embs[(size_t)x2 * NC + j];
        out[(size_t)(b0 + 3) * NC + j] =
            (1.0f / (1.0f + __expf(-s3))) * embs[(size_t)x3 * NC + j];
    }
}

// ---------------------------------------------------------------------------
// fallback (round-2-proven structure): fused per-sample kernel, fp32 gather
__global__ __launch_bounds__(NT, 4)
void esa_fallback(const int* __restrict__ x, const int* __restrict__ ctx,
                  const float* __restrict__ embs, const float* __restrict__ b1,
                  const float* __restrict__ b2, const ushort* __restrict__ W1T,
                  const ushort* __restrict__ W2T, float* __restrict__ out) {
    __shared__ short A[CTXL * ASTR];
    __shared__ float xemb[NC];
    __shared__ float pooled[NH];
    const int b = blockIdx.x, tid = threadIdx.x;
    const int wave = tid >> 6, lane = tid & 63, l15 = lane & 15, lhi = lane >> 4;

    const int r = tid >> 2, cq = tid & 3;
    if (r < CTXL) {
        const int row = ctx[b * CTXL + r];
        const float* src = embs + (size_t)row * NC;
        #pragma unroll
        for (int i = 0; i < 19; ++i) {
            const int c = cq + 4 * i;
            if (c < 75) {
                const float4 v = *(const float4*)(src + c * 4);
                uint2 p;
                p.x = (unsigned)f2bf(v.x) | ((unsigned)f2bf(v.y) << 16);
                p.y = (unsigned)f2bf(v.z) | ((unsigned)f2bf(v.w) << 16);
                *(uint2*)((char*)A + (size_t)r * (ASTR * 2) + c * 8) = p;
            }
        }
        #pragma unroll
        for (int k = cq; k < 5; k += 4)
            *(uint2*)((char*)A + (size_t)r * (ASTR * 2) + 600 + k * 8) = make_uint2(0u, 0u);
    }
    { const int row = x[b];
      if (tid < NC / 4) ((float4*)xemb)[tid] = ((const float4*)(embs + (size_t)row * NC))[tid]; }
    __syncthreads();

    f32x4 acc[4][4];
    #pragma unroll
    for (int mt = 0; mt < 4; ++mt)
        #pragma unroll
        for (int nt = 0; nt < 4; ++nt) acc[mt][nt] = (f32x4){0.f, 0.f, 0.f, 0.f};
    int abyte[4];
    #pragma unroll
    for (int mt = 0; mt < 4; ++mt) {
        int rr = mt * 16 + l15; if (rr >= CTXL) rr = 0;
        abyte[mt] = rr * (ASTR * 2) + lhi * 16;
    }
    const ushort* wb = W1T + (size_t)(wave * 64 + l15) * KPAD + lhi * 8;
    #pragma unroll
    for (int ks = 0; ks < KPAD / 32; ++ks) {
        s16x8 af[4], bfr[4];
        #pragma unroll
        for (int mt = 0; mt < 4; ++mt)
            af[mt] = *(const s16x8*)((const char*)A + abyte[mt] + ks * 64);
        #pragma unroll
        for (int nt = 0; nt < 4; ++nt)
            bfr[nt] = *(const s16x8*)(wb + nt * 16 * KPAD + ks * 32);
        #pragma unroll
        for (int mt = 0; mt < 4; ++mt)
            #pragma unroll
            for (int nt = 0; nt < 4; ++nt)
                acc[mt][nt] = __builtin_amdgcn_mfma_f32_16x16x32_bf16(
                    af[mt], bfr[nt], acc[mt][nt], 0, 0, 0);
    }
    #pragma unroll
    for (int nt = 0; nt < 4; ++nt) {
        const float bb = b1[wave * 64 + nt * 16 + l15];
        float s = 0.0f;
        #pragma unroll
        for (int mt = 0; mt < 4; ++mt)
            #pragma unroll
            for (int q = 0; q < 4; ++q) {
                const int row = mt * 16 + lhi * 4 + q;
                const float v = fmaxf(acc[mt][nt][q] + bb, 0.0f);
                s += (row < CTXL) ? v : 0.0f;
            }
        s += __shfl_xor(s, 16);
        s += __shfl_xor(s, 32);
        if (lhi == 0) pooled[wave * 64 + nt * 16 + l15] = s * (1.0f / CTXL);
    }
    __syncthreads();
    for (int j = tid; j < NC; j += NT) {
        float s = b2[j];
        const s16x8* wrow = (const s16x8*)(W2T + (size_t)j * NH);
        #pragma unroll 8
        for (int c = 0; c < NH / 8; ++c) {
            const s16x8 w8 = wrow[c];
            const float4 p0 = *(const float4*)(&pooled[c * 8]);
            const float4 p1 = *(const float4*)(&pooled[c * 8 + 4]);
            s = fmaf(p0.x, bf2f((ushort)w8[0]), s);
            s = fmaf(p0.y, bf2f((ushort)w8[1]), s);
            s = fmaf(p0.z, bf2f((ushort)w8[2]), s);
            s = fmaf(p0.w, bf2f((ushort)w8[3]), s);
            s = fmaf(p1.x, bf2f((ushort)w8[4]), s);
            s = fmaf(p1.y, bf2f((ushort)w8[5]), s);
            s = fmaf(p1.z, bf2f((ushort)w8[6]), s);
            s = fmaf(p1.w, bf2f((ushort)w8[7]), s);
        }
        const float g = 1.0f / (1.0f + __expf(-s));
        out[(size_t)b * NC + j] = g * xemb[j];
    }
}

extern "C" void kernel_launch(void* const* d_in, const int* in_sizes, int n_in,
                              void* d_out, int out_size, void* d_ws, size_t ws_size,
                              hipStream_t stream) {
    const int*   x    = (const int*)d_in[0];
    const int*   ctx  = (const int*)d_in[1];
    const float* embs = (const float*)d_in[2];
    const float* W1   = (const float*)d_in[3];
    const float* b1   = (const float*)d_in[4];
    const float* W2   = (const float*)d_in[5];
    const float* b2   = (const float*)d_in[6];
    float* out = (float*)d_out;

    const int B    = in_sizes[0];
    const int ntok = in_sizes[2] / NC;

    const size_t h_bytes   = (size_t)ntok * NH * 2;   // 51.2 MB
    const size_t w1t_bytes = (size_t)NH * KPAD * 2;   // 160 KB
    const size_t w2t_bytes = (size_t)NC * NH * 2;     // 150 KB

    if (ws_size >= h_bytes + w1t_bytes + w2t_bytes && (B & 3) == 0) {
        ushort* H   = (ushort*)d_ws;
        ushort* W1T = (ushort*)((char*)d_ws + h_bytes);
        ushort* W2T = (ushort*)((char*)d_ws + h_bytes + w1t_bytes);
        convert_w<<<KPAD + NC, NT, 0, stream>>>(W1, W2, W1T, W2T);
        const int ntiles = (ntok + MR - 1) / MR;
        k1_hidden<<<ntiles, NT, 0, stream>>>(embs, b1, W1T, H, ntok);
        k2_pool<<<B / 4, NT, 0, stream>>>(x, ctx, embs, H, W2T, b2, out);
    } else {
        ushort* W1T = (ushort*)d_ws;
        ushort* W2T = (ushort*)((char*)d_ws + w1t_bytes);
        convert_w<<<KPAD + NC, NT, 0, stream>>>(W1, W2, W1T, W2T);
        esa_fallback<<<B, NT, 0, stream>>>(x, ctx, embs, b1, b2, W1T, W2T, out);
    }
}

// Round 14
// 91.643 us; speedup vs baseline: 1.6070x; 1.6070x over previous
//
#include <hip/hip_runtime.h>
#include <hip/hip_bf16.h>
#include <cmath>

#define CTXL 50
#define NC 300    // NCOND
#define NH 256    // NHID
#define NT 256    // threads (k2 / fallback)
#define K1T 512   // threads (k1): 8 waves, wave owns 32 H-cols
#define KPAD 320  // K padded to 10 k-steps of 32
#define NKS 10
#define MR 32     // K1 rows per tile; 32*320 fp32 = 40 KiB per buffer
#define ASTR 328  // fallback LDS stride (shorts)

typedef float  f32x4 __attribute__((ext_vector_type(4)));
typedef short  s16x8 __attribute__((ext_vector_type(8)));
typedef short  s16x4 __attribute__((ext_vector_type(4)));

__device__ __forceinline__ ushort f2bf(float f) {
    unsigned u = __float_as_uint(f);
    unsigned r = (u + 0x7FFFu + ((u >> 16) & 1u)) >> 16;   // RNE
    return (ushort)r;
}
__device__ __forceinline__ float bf2f(ushort u) {
    return __uint_as_float(((unsigned)u) << 16);
}
__device__ __forceinline__ short f2bf_hw(float f) {       // HW RNE cvt
    union { __hip_bfloat16 h; short s; } u;
    u.h = __float2bfloat16(f);
    return u.s;
}
__device__ __forceinline__ s16x8 cvt8(f32x4 a, f32x4 b) {
    s16x8 r;
    r[0] = f2bf_hw(a[0]); r[1] = f2bf_hw(a[1]);
    r[2] = f2bf_hw(a[2]); r[3] = f2bf_hw(a[3]);
    r[4] = f2bf_hw(b[0]); r[5] = f2bf_hw(b[1]);
    r[6] = f2bf_hw(b[2]); r[7] = f2bf_hw(b[3]);
    return r;
}

// ---------------------------------------------------------------------------
// prepass: W1 [300][256] -> W1T bf16 [256][320] (k>=300 rows ZERO — this makes
// K1's garbage-padded A chunks don't-care); W2 -> W2T bf16 [300][256]
__global__ void convert_w(const float* __restrict__ W1, const float* __restrict__ W2,
                          ushort* __restrict__ W1T, ushort* __restrict__ W2T) {
    const int t  = threadIdx.x;
    const int bi = blockIdx.x;
    if (bi < KPAD) {
        W1T[(size_t)t * KPAD + bi] = (bi < NC) ? f2bf(W1[(size_t)bi * NH + t]) : (ushort)0;
    } else {
        const int j = bi - KPAD;           // < 300
        W2T[(size_t)j * NH + t] = f2bf(W2[(size_t)t * NC + j]);
    }
}

// ---------------------------------------------------------------------------
// K1 async stage: per wave 5x global_load_lds_dwordx4 into fp32 LDS tile.
// Linear LDS chunk p=(wave*5+i)*64+lane; logical (row = p/80, c' = p%80);
// data chunk c = c' ^ (row&7) (XOR swizzle, applied identically on ds_read).
// Chunks c>=75 (k>=300) read a dummy valid address — W1T k>=300 is zero.
// Plain inline function, nothing held in registers (r11 lambda/scratch lesson).
__device__ __forceinline__ void k1_stage(const float* __restrict__ embs,
                                         float* dstbuf, int m0, int ntok,
                                         int wave, int lane) {
    #pragma unroll
    for (int i = 0; i < 5; ++i) {
        const int p   = (wave * 5 + i) * 64 + lane;
        const int row = p / 80;
        const int cp  = p - row * 80;
        const int cc  = cp ^ (row & 7);
        int rg = m0 + row; if (rg >= ntok) rg = ntok - 1;
        const float* g = (cc < 75) ? (embs + (size_t)rg * NC + cc * 4) : embs;
        __builtin_amdgcn_global_load_lds(
            (const __attribute__((address_space(1))) unsigned int*)g,
            (__attribute__((address_space(3))) unsigned int*)(dstbuf + (wave * 5 + i) * 256),
            16, 0, 0);
    }
}

// K1 v7: H = relu(embs @ W1 + b1), async-pipelined.
// 8 waves x 32 cols; wf preload 2ct x 10ks = 80 VGPR (static idx); double-
// buffered fp32 LDS (2 x 40KiB); per iter: barrier (drains DMA+ds) -> issue
// next tile's DMA -> compute current (ds_read fp32 + HW cvt + MFMA from regs)
// -> direct swapped-layout bf16 store. DMA latency hides under compute.
__global__ __launch_bounds__(K1T, 2)
void k1_hidden(const float* __restrict__ embs,
               const float* __restrict__ b1,
               const ushort* __restrict__ W1T,
               ushort* __restrict__ H, int ntok, int ntiles) {
    __shared__ float Abuf[2][MR * 320];   // 81920 B
    const int tid  = threadIdx.x;
    const int wave = tid >> 6;
    const int lane = tid & 63;
    const int l15  = lane & 15;
    const int lhi  = lane >> 4;

    // wf preload: this wave's 32 cols, all K (80 VGPR)
    const ushort* wbase = W1T + (size_t)(wave * 32 + l15) * KPAD + lhi * 8;
    s16x8 wf[2][NKS];
    #pragma unroll
    for (int ct = 0; ct < 2; ++ct)
        #pragma unroll
        for (int ks = 0; ks < NKS; ++ks)
            wf[ct][ks] = *(const s16x8*)(wbase + ct * 16 * KPAD + ks * 32);

    f32x4 bfrag[2];
    #pragma unroll
    for (int ct = 0; ct < 2; ++ct)
        bfrag[ct] = *(const f32x4*)(b1 + wave * 32 + ct * 16 + 4 * lhi);

    const int t0 = blockIdx.x;
    if (t0 >= ntiles) return;

    k1_stage(embs, &Abuf[0][0], t0 * MR, ntok, wave, lane);   // prologue

    int cur = 0;
    for (int t = t0; t < ntiles; t += gridDim.x) {
        __syncthreads();               // drains DMA into buf[cur] + prior ds reads
        const int tn = t + gridDim.x;
        if (tn < ntiles)
            k1_stage(embs, &Abuf[cur ^ 1][0], tn * MR, ntok, wave, lane);  // fire & forget

        const float* Ab = &Abuf[cur][0];
        f32x4 acc[2][2];
        #pragma unroll
        for (int ct = 0; ct < 2; ++ct)
            #pragma unroll
            for (int rt = 0; rt < 2; ++rt)
                acc[ct][rt] = (f32x4){0.f, 0.f, 0.f, 0.f};

        #pragma unroll
        for (int ks = 0; ks < NKS; ++ks) {
            s16x8 ef[2];
            #pragma unroll
            for (int rt = 0; rt < 2; ++rt) {
                const int row = rt * 16 + l15;
                const int s   = row & 7;
                const int c0  = ks * 8 + lhi * 2;
                const f32x4 a0 = *(const f32x4*)(Ab + row * 320 + (((c0    ) ^ s) << 2));
                const f32x4 a1 = *(const f32x4*)(Ab + row * 320 + (((c0 + 1) ^ s) << 2));
                ef[rt] = cvt8(a0, a1);
            }
            #pragma unroll
            for (int ct = 0; ct < 2; ++ct)
                #pragma unroll
                for (int rt = 0; rt < 2; ++rt)
                    acc[ct][rt] = __builtin_amdgcn_mfma_f32_16x16x32_bf16(
                        wf[ct][ks], ef[rt], acc[ct][rt], 0, 0, 0);
        }

        // epilogue: relu(acc+b1) -> bf16, direct ushort4 stores
        // swapped-MFMA layout: D-col(l15)=emb row, D-row(4*lhi+q)=W1 col
        const int m0 = t * MR;
        #pragma unroll
        for (int ct = 0; ct < 2; ++ct) {
            const int col = wave * 32 + ct * 16 + 4 * lhi;
            #pragma unroll
            for (int rt = 0; rt < 2; ++rt) {
                const int row = m0 + rt * 16 + l15;
                if (row < ntok) {
                    ushort4 h;
                    h.x = f2bf(fmaxf(acc[ct][rt][0] + bfrag[ct][0], 0.0f));
                    h.y = f2bf(fmaxf(acc[ct][rt][1] + bfrag[ct][1], 0.0f));
                    h.z = f2bf(fmaxf(acc[ct][rt][2] + bfrag[ct][2], 0.0f));
                    h.w = f2bf(fmaxf(acc[ct][rt][3] + bfrag[ct][3], 0.0f));
                    *(ushort4*)(H + (size_t)row * NH + col) = h;
                }
            }
        }
        cur ^= 1;
    }
}

// ---------------------------------------------------------------------------
// K2: out[b] = sigmoid(mean_l H[ctx[b,l]] @ W2 + b2) * embs[x[b]]
// 4 samples per block; W2T row stream shared by 4 gates.
__global__ __launch_bounds__(NT, 4)
void k2_pool(const int* __restrict__ x,
             const int* __restrict__ ctx,
             const float* __restrict__ embs,
             const ushort* __restrict__ H,
             const ushort* __restrict__ W2T,
             const float* __restrict__ b2,
             float* __restrict__ out) {
    __shared__ int   ctxs[4 * CTXL];
    __shared__ float pooled[4][NH];
    const int b0   = blockIdx.x * 4;
    const int tid  = threadIdx.x;
    const int wave = tid >> 6;
    const int lane = tid & 63;

    if (tid < 4 * CTXL) ctxs[tid] = ctx[b0 * CTXL + tid];
    __syncthreads();

    {
        float4 ps = make_float4(0.f, 0.f, 0.f, 0.f);
        #pragma unroll 10
        for (int i = 0; i < CTXL; ++i) {
            const int row = ctxs[wave * CTXL + i];
            const s16x4 h4 = *(const s16x4*)(H + (size_t)row * NH + lane * 4);
            ps.x += bf2f((ushort)h4[0]);
            ps.y += bf2f((ushort)h4[1]);
            ps.z += bf2f((ushort)h4[2]);
            ps.w += bf2f((ushort)h4[3]);
        }
        ps.x *= (1.0f / CTXL); ps.y *= (1.0f / CTXL);
        ps.z *= (1.0f / CTXL); ps.w *= (1.0f / CTXL);
        *(float4*)(&pooled[wave][lane * 4]) = ps;
    }
    __syncthreads();

    const int x0 = x[b0], x1 = x[b0 + 1], x2 = x[b0 + 2], x3 = x[b0 + 3];
    for (int j = tid; j < NC; j += NT) {
        float s0 = b2[j], s1 = s0, s2 = s0, s3 = s0;
        const s16x8* wrow = (const s16x8*)(W2T + (size_t)j * NH);
        #pragma unroll 8
        for (int c = 0; c < NH / 8; ++c) {
            const s16x8 w8 = wrow[c];
            #pragma unroll
            for (int q = 0; q < 8; ++q) {
                const float wv = bf2f((ushort)w8[q]);
                s0 = fmaf(pooled[0][c * 8 + q], wv, s0);
                s1 = fmaf(pooled[1][c * 8 + q], wv, s1);
                s2 = fmaf(pooled[2][c * 8 + q], wv, s2);
                s3 = fmaf(pooled[3][c * 8 + q], wv, s3);
            }
        }
        out[(size_t)(b0 + 0) * NC + j] =
            (1.0f / (1.0f + __expf(-s0))) * embs[(size_t)x0 * NC + j];
        out[(size_t)(b0 + 1) * NC + j] =
            (1.0f / (1.0f + __expf(-s1))) * embs[(size_t)x1 * NC + j];
        out[(size_t)(b0 + 2) * NC + j] =
            (1.0f / (1.0f + __expf(-s2))) * embs[(size_t)x2 * NC + j];
        out[(size_t)(b0 + 3) * NC + j] =
            (1.0f / (1.0f + __expf(-s3))) * embs[(size_t)x3 * NC + j];
    }
}

// ---------------------------------------------------------------------------
// fallback (round-2-proven structure): fused per-sample kernel, fp32 gather
__global__ __launch_bounds__(NT, 4)
void esa_fallback(const int* __restrict__ x, const int* __restrict__ ctx,
                  const float* __restrict__ embs, const float* __restrict__ b1,
                  const float* __restrict__ b2, const ushort* __restrict__ W1T,
                  const ushort* __restrict__ W2T, float* __restrict__ out) {
    __shared__ short A[CTXL * ASTR];
    __shared__ float xemb[NC];
    __shared__ float pooled[NH];
    const int b = blockIdx.x, tid = threadIdx.x;
    const int wave = tid >> 6, lane = tid & 63, l15 = lane & 15, lhi = lane >> 4;

    const int r = tid >> 2, cq = tid & 3;
    if (r < CTXL) {
        const int row = ctx[b * CTXL + r];
        const float* src = embs + (size_t)row * NC;
        #pragma unroll
        for (int i = 0; i < 19; ++i) {
            const int c = cq + 4 * i;
            if (c < 75) {
                const float4 v = *(const float4*)(src + c * 4);
                uint2 p;
                p.x = (unsigned)f2bf(v.x) | ((unsigned)f2bf(v.y) << 16);
                p.y = (unsigned)f2bf(v.z) | ((unsigned)f2bf(v.w) << 16);
                *(uint2*)((char*)A + (size_t)r * (ASTR * 2) + c * 8) = p;
            }
        }
        #pragma unroll
        for (int k = cq; k < 5; k += 4)
            *(uint2*)((char*)A + (size_t)r * (ASTR * 2) + 600 + k * 8) = make_uint2(0u, 0u);
    }
    { const int row = x[b];
      if (tid < NC / 4) ((float4*)xemb)[tid] = ((const float4*)(embs + (size_t)row * NC))[tid]; }
    __syncthreads();

    f32x4 acc[4][4];
    #pragma unroll
    for (int mt = 0; mt < 4; ++mt)
        #pragma unroll
        for (int nt = 0; nt < 4; ++nt) acc[mt][nt] = (f32x4){0.f, 0.f, 0.f, 0.f};
    int abyte[4];
    #pragma unroll
    for (int mt = 0; mt < 4; ++mt) {
        int rr = mt * 16 + l15; if (rr >= CTXL) rr = 0;
        abyte[mt] = rr * (ASTR * 2) + lhi * 16;
    }
    const ushort* wb = W1T + (size_t)(wave * 64 + l15) * KPAD + lhi * 8;
    #pragma unroll
    for (int ks = 0; ks < KPAD / 32; ++ks) {
        s16x8 af[4], bfr[4];
        #pragma unroll
        for (int mt = 0; mt < 4; ++mt)
            af[mt] = *(const s16x8*)((const char*)A + abyte[mt] + ks * 64);
        #pragma unroll
        for (int nt = 0; nt < 4; ++nt)
            bfr[nt] = *(const s16x8*)(wb + nt * 16 * KPAD + ks * 32);
        #pragma unroll
        for (int mt = 0; mt < 4; ++mt)
            #pragma unroll
            for (int nt = 0; nt < 4; ++nt)
                acc[mt][nt] = __builtin_amdgcn_mfma_f32_16x16x32_bf16(
                    af[mt], bfr[nt], acc[mt][nt], 0, 0, 0);
    }
    #pragma unroll
    for (int nt = 0; nt < 4; ++nt) {
        const float bb = b1[wave * 64 + nt * 16 + l15];
        float s = 0.0f;
        #pragma unroll
        for (int mt = 0; mt < 4; ++mt)
            #pragma unroll
            for (int q = 0; q < 4; ++q) {
                const int row = mt * 16 + lhi * 4 + q;
                const float v = fmaxf(acc[mt][nt][q] + bb, 0.0f);
                s += (row < CTXL) ? v : 0.0f;
            }
        s += __shfl_xor(s, 16);
        s += __shfl_xor(s, 32);
        if (lhi == 0) pooled[wave * 64 + nt * 16 + l15] = s * (1.0f / CTXL);
    }
    __syncthreads();
    for (int j = tid; j < NC; j += NT) {
        float s = b2[j];
        const s16x8* wrow = (const s16x8*)(W2T + (size_t)j * NH);
        #pragma unroll 8
        for (int c = 0; c < NH / 8; ++c) {
            const s16x8 w8 = wrow[c];
            const float4 p0 = *(const float4*)(&pooled[c * 8]);
            const float4 p1 = *(const float4*)(&pooled[c * 8 + 4]);
            s = fmaf(p0.x, bf2f((ushort)w8[0]), s);
            s = fmaf(p0.y, bf2f((ushort)w8[1]), s);
            s = fmaf(p0.z, bf2f((ushort)w8[2]), s);
            s = fmaf(p0.w, bf2f((ushort)w8[3]), s);
            s = fmaf(p1.x, bf2f((ushort)w8[4]), s);
            s = fmaf(p1.y, bf2f((ushort)w8[5]), s);
            s = fmaf(p1.z, bf2f((ushort)w8[6]), s);
            s = fmaf(p1.w, bf2f((ushort)w8[7]), s);
        }
        const float g = 1.0f / (1.0f + __expf(-s));
        out[(size_t)b * NC + j] = g * xemb[j];
    }
}

extern "C" void kernel_launch(void* const* d_in, const int* in_sizes, int n_in,
                              void* d_out, int out_size, void* d_ws, size_t ws_size,
                              hipStream_t stream) {
    const int*   x    = (const int*)d_in[0];
    const int*   ctx  = (const int*)d_in[1];
    const float* embs = (const float*)d_in[2];
    const float* W1   = (const float*)d_in[3];
    const float* b1   = (const float*)d_in[4];
    const float* W2   = (const float*)d_in[5];
    const float* b2   = (const float*)d_in[6];
    float* out = (float*)d_out;

    const int B    = in_sizes[0];
    const int ntok = in_sizes[2] / NC;

    const size_t h_bytes   = (size_t)ntok * NH * 2;   // 51.2 MB
    const size_t w1t_bytes = (size_t)NH * KPAD * 2;   // 160 KB
    const size_t w2t_bytes = (size_t)NC * NH * 2;     // 150 KB

    if (ws_size >= h_bytes + w1t_bytes + w2t_bytes && (B & 3) == 0) {
        ushort* H   = (ushort*)d_ws;
        ushort* W1T = (ushort*)((char*)d_ws + h_bytes);
        ushort* W2T = (ushort*)((char*)d_ws + h_bytes + w1t_bytes);
        convert_w<<<KPAD + NC, NT, 0, stream>>>(W1, W2, W1T, W2T);
        const int ntiles = (ntok + MR - 1) / MR;
        const int k1grid = (ntiles < 256) ? ntiles : 256;   // 1 block/CU, grid-stride
        k1_hidden<<<k1grid, K1T, 0, stream>>>(embs, b1, W1T, H, ntok, ntiles);
        k2_pool<<<B / 4, NT, 0, stream>>>(x, ctx, embs, H, W2T, b2, out);
    } else {
        ushort* W1T = (ushort*)d_ws;
        ushort* W2T = (ushort*)((char*)d_ws + w1t_bytes);
        convert_w<<<KPAD + NC, NT, 0, stream>>>(W1, W2, W1T, W2T);
        esa_fallback<<<B, NT, 0, stream>>>(x, ctx, embs, b1, b2, W1T, W2T, out);
    }
}